// Round 2
// baseline (37018.732 us; speedup 1.0000x reference)
//
#include <hip/hip_runtime.h>
#include <hip/hip_cooperative_groups.h>
#include <cstdint>
#include <cstddef>

namespace cg = cooperative_groups;

#define EMBD 1024
#define HIDD 1024
#define G4   4096
#define VOC  32000
#define SEQL 128
#define GN   64
#define NR   64
#define GRID 1024

#define JAX_PARTITIONABLE 1

// ---------------- threefry2x32 (JAX-compatible, 20 rounds) ----------------
__device__ __forceinline__ uint32_t rotl32(uint32_t v, int d) { return (v << d) | (v >> (32 - d)); }

__device__ inline void threefry2x32(uint32_t k0, uint32_t k1, uint32_t x0, uint32_t x1,
                                    uint32_t& o0, uint32_t& o1) {
  uint32_t ks2 = k0 ^ k1 ^ 0x1BD11BDAu;
#define TF_ROUND(r) { x0 += x1; x1 = rotl32(x1, r); x1 ^= x0; }
  x0 += k0;  x1 += k1;
  TF_ROUND(13) TF_ROUND(15) TF_ROUND(26) TF_ROUND(6)
  x0 += k1;  x1 += ks2 + 1u;
  TF_ROUND(17) TF_ROUND(29) TF_ROUND(16) TF_ROUND(24)
  x0 += ks2; x1 += k0 + 2u;
  TF_ROUND(13) TF_ROUND(15) TF_ROUND(26) TF_ROUND(6)
  x0 += k0;  x1 += k1 + 3u;
  TF_ROUND(17) TF_ROUND(29) TF_ROUND(16) TF_ROUND(24)
  x0 += k1;  x1 += ks2 + 4u;
  TF_ROUND(13) TF_ROUND(15) TF_ROUND(26) TF_ROUND(6)
  x0 += ks2; x1 += k0 + 5u;
#undef TF_ROUND
  o0 = x0; o1 = x1;
}

__device__ inline uint32_t rng_bits(uint32_t k0, uint32_t k1, uint32_t idx) {
#if JAX_PARTITIONABLE
  uint32_t h0, h1; threefry2x32(k0, k1, 0u, idx, h0, h1);
  return h0 ^ h1;
#else
  uint32_t h0, h1;
  if (idx < (VOC / 2)) { threefry2x32(k0, k1, idx, idx + (VOC / 2), h0, h1); return h0; }
  else                 { threefry2x32(k0, k1, idx - (VOC / 2), idx, h0, h1); return h1; }
#endif
}

__device__ inline float gumbel_of(uint32_t k0, uint32_t k1, uint32_t idx) {
  uint32_t bits = rng_bits(k0, k1, idx);
  float u = __uint_as_float((bits >> 9) | 0x3f800000u) - 1.0f;
  u = fmaxf(u, 1.17549435e-38f);
  return -logf(-logf(u));
}

__device__ inline unsigned long long packCand(float v, int idx) {
  uint32_t u = __float_as_uint(v);
  u = (u & 0x80000000u) ? ~u : (u | 0x80000000u);
  return ((unsigned long long)u << 32) | (unsigned long long)(0xFFFFFFFFu - (uint32_t)idx);
}

__device__ inline float sigf(float x) { return 1.0f / (1.0f + expf(-x)); }

// ---------------- init: split keys of key(123) ----------------
__global__ void k_init(uint2* keys) {
  int t = threadIdx.x;
  if (t < NR + 1) {
    uint32_t a, b; threefry2x32(0u, 123u, 0u, (uint32_t)t, a, b);
    keys[t] = make_uint2(a, b);
  }
}

// ---------------- gather prefix embeddings ----------------
__global__ void k_gather(const float* __restrict__ emb, const int* __restrict__ sent,
                         float* __restrict__ X) {
  int m = blockIdx.x;
  int row = sent[m];
  const float4* s = (const float4*)(emb + (size_t)row * EMBD);
  float4* d = (float4*)(X + (size_t)m * EMBD);
  d[threadIdx.x] = s[threadIdx.x];
}

// ---------------- GEMM: C[64][N] = A[64][1024] @ B[N][1024]^T (+bias), 32-col tiles ----------------
__global__ __launch_bounds__(256) void k_gemm_n32(const float* __restrict__ A,
                                                  const float* __restrict__ B,
                                                  const float* __restrict__ bias,
                                                  float* __restrict__ C, int ldc) {
  __shared__ float As[64][33];
  __shared__ float Bs[32][33];
  int n0 = blockIdx.x * 32;
  int tn = threadIdx.x & 15, tm = threadIdx.x >> 4;
  float acc[4][2] = {{0.f}};
  for (int k0 = 0; k0 < 1024; k0 += 32) {
    for (int f = threadIdx.x; f < 512; f += 256) {
      int r = f >> 3, c4 = (f & 7) << 2;
      float4 v = *(const float4*)(A + (size_t)r * 1024 + k0 + c4);
      As[r][c4 + 0] = v.x; As[r][c4 + 1] = v.y; As[r][c4 + 2] = v.z; As[r][c4 + 3] = v.w;
    }
    {
      int f = threadIdx.x;
      int r = f >> 3, c4 = (f & 7) << 2;
      float4 u = *(const float4*)(B + (size_t)(n0 + r) * 1024 + k0 + c4);
      Bs[r][c4 + 0] = u.x; Bs[r][c4 + 1] = u.y; Bs[r][c4 + 2] = u.z; Bs[r][c4 + 3] = u.w;
    }
    __syncthreads();
#pragma unroll
    for (int kk = 0; kk < 32; ++kk) {
      float a0 = As[tm * 4 + 0][kk], a1 = As[tm * 4 + 1][kk];
      float a2 = As[tm * 4 + 2][kk], a3 = As[tm * 4 + 3][kk];
      float b0 = Bs[tn * 2 + 0][kk], b1 = Bs[tn * 2 + 1][kk];
      acc[0][0] += a0 * b0; acc[0][1] += a0 * b1;
      acc[1][0] += a1 * b0; acc[1][1] += a1 * b1;
      acc[2][0] += a2 * b0; acc[2][1] += a2 * b1;
      acc[3][0] += a3 * b0; acc[3][1] += a3 * b1;
    }
    __syncthreads();
  }
#pragma unroll
  for (int i = 0; i < 4; ++i)
#pragma unroll
    for (int j = 0; j < 2; ++j) {
      int m = tm * 4 + i, n = n0 + tn * 2 + j;
      C[(size_t)m * ldc + n] = acc[i][j] + (bias ? bias[n] : 0.0f);
    }
}

// ---------------- fused prefix: 64 LSTM steps, 1 grid.sync each ----------------
__global__ __launch_bounds__(256, 4) void k_prefix_coop(const float* __restrict__ Whh,
                                                        const float* __restrict__ bih,
                                                        const float* __restrict__ bhh,
                                                        const float* __restrict__ gx,
                                                        float* gates2,
                                                        float* lstm_out,
                                                        float* cbuf_out) {
  cg::grid_group grid = cg::this_grid();
  __shared__ float hS[1024];
  __shared__ float cS[1024];
  int tid = threadIdx.x;
  for (int j = tid; j < 1024; j += 256) { hS[j] = 0.0f; cS[j] = 0.0f; }
  int wave = tid >> 6, lane = tid & 63;
  int r = blockIdx.x * 4 + wave;          // 0..4095, one gate row per wave
  const float4* w4 = (const float4*)(Whh + (size_t)r * 1024);
  float4 wv[4];
#pragma unroll
  for (int q = 0; q < 4; ++q) wv[q] = w4[lane + (q << 6)];
  float bihr = bih[r], bhhr = bhh[r];
  __syncthreads();
  for (int t = 0; t < GN; ++t) {
    // Phase A: gate dot (h from LDS, W row resident in VGPRs)
    float a = 0.0f;
#pragma unroll
    for (int q = 0; q < 4; ++q) {
      float4 h = ((const float4*)hS)[lane + (q << 6)];
      float4 w = wv[q];
      a += w.x * h.x + w.y * h.y + w.z * h.z + w.w * h.w;
    }
#pragma unroll
    for (int off = 32; off; off >>= 1) a += __shfl_xor(a, off, 64);
    if (lane == 0) gates2[(size_t)(t & 1) * G4 + r] = a + gx[(size_t)t * G4 + r] + bihr + bhhr;
    __threadfence();
    grid.sync();
    // Phase B: redundant per-block h/c update from gates
    const float* g = gates2 + (size_t)(t & 1) * G4;
    for (int j = tid; j < 1024; j += 256) {
      float gi = g[j], gf = g[j + 1024], gg = g[j + 2048], go = g[j + 3072];
      float cn = sigf(gf) * cS[j] + sigf(gi) * tanhf(gg);
      cS[j] = cn;
      float hn = sigf(go) * tanhf(cn);
      hS[j] = hn;
      if (blockIdx.x == 0) {
        lstm_out[(size_t)t * HIDD + j] = hn;
        if (t == GN - 1) cbuf_out[j] = cn;
      }
    }
    __syncthreads();
  }
}

// ---------------- fused rollout: initial sample + 64 (LSTM + logits + sample) ----------------
__global__ __launch_bounds__(256, 4) void k_rollout_coop(const float* __restrict__ Wih,
                                                         const float* __restrict__ Whh,
                                                         const float* __restrict__ bih,
                                                         const float* __restrict__ bhh,
                                                         const float* __restrict__ emb,
                                                         const float* __restrict__ Wtag,
                                                         const float* __restrict__ btag,
                                                         const float* __restrict__ h_init,
                                                         const float* __restrict__ c_init,
                                                         const float* __restrict__ row63,
                                                         const uint2* __restrict__ keys,
                                                         float* gates2,
                                                         unsigned long long* partials,
                                                         float* out) {
  cg::grid_group grid = cg::this_grid();
  __shared__ float hS[1024];
  __shared__ float cS[1024];
  __shared__ unsigned long long redU[256];
  int tid = threadIdx.x, wave = tid >> 6, lane = tid & 63;
  for (int j = tid; j < 1024; j += 256) { hS[j] = h_init[j]; cS[j] = c_init[j]; }
  // ---- initial sample from tag_prefix row 63 ----
  unsigned long long best = 0ull;
  if (blockIdx.x < VOC / 256) {
    int v = blockIdx.x * 256 + tid;
    uint2 K = keys[0];
    float y = row63[v] + gumbel_of(K.x, K.y, (uint32_t)v);
    best = packCand(y, v);
  }
  redU[tid] = best;
  __syncthreads();
  for (int s = 128; s; s >>= 1) {
    if (tid < s && redU[tid + s] > redU[tid]) redU[tid] = redU[tid + s];
    __syncthreads();
  }
  if (tid == 0) partials[blockIdx.x] = redU[0];
  __threadfence();
  grid.sync();
  // all blocks redundantly reduce partials -> tok
  unsigned long long b0 = 0ull;
  for (int i = tid; i < GRID; i += 256) { unsigned long long v = partials[i]; if (v > b0) b0 = v; }
  redU[tid] = b0;
  __syncthreads();
  for (int s = 128; s; s >>= 1) {
    if (tid < s && redU[tid + s] > redU[tid]) redU[tid] = redU[tid + s];
    __syncthreads();
  }
  int tok = (int)(0xFFFFFFFFu - (uint32_t)(redU[0] & 0xFFFFFFFFull));
  __syncthreads();
  // ---- preload LSTM weight rows (fixed per wave) ----
  int r = blockIdx.x * 4 + wave;  // 0..4095
  const float4* wi4 = (const float4*)(Wih + (size_t)r * 1024);
  const float4* wh4 = (const float4*)(Whh + (size_t)r * 1024);
  float4 wiv[4], whv[4];
#pragma unroll
  for (int q = 0; q < 4; ++q) { wiv[q] = wi4[lane + (q << 6)]; whv[q] = wh4[lane + (q << 6)]; }
  float bihr = bih[r], bhhr = bhh[r];

  for (int t = 0; t < NR; ++t) {
    // Phase A: LSTM gate dot (x = emb[tok], h from LDS)
    const float4* x4 = (const float4*)(emb + (size_t)tok * EMBD);
    float a = 0.0f;
#pragma unroll
    for (int q = 0; q < 4; ++q) {
      float4 w = wiv[q];
      float4 x = x4[lane + (q << 6)];
      a += w.x * x.x + w.y * x.y + w.z * x.z + w.w * x.w;
      w = whv[q];
      float4 h = ((const float4*)hS)[lane + (q << 6)];
      a += w.x * h.x + w.y * h.y + w.z * h.z + w.w * h.w;
    }
#pragma unroll
    for (int off = 32; off; off >>= 1) a += __shfl_xor(a, off, 64);
    if (lane == 0) gates2[(size_t)(t & 1) * G4 + r] = a + bihr + bhhr;
    __threadfence();
    grid.sync();
    // Phase B: redundant h/c update
    const float* g = gates2 + (size_t)(t & 1) * G4;
    for (int j = tid; j < 1024; j += 256) {
      float gi = g[j], gf = g[j + 1024], gg = g[j + 2048], go = g[j + 3072];
      float cn = sigf(gf) * cS[j] + sigf(gi) * tanhf(gg);
      cS[j] = cn;
      hS[j] = sigf(go) * tanhf(cn);
    }
    __syncthreads();
    // Phase C: logits matvec + gumbel + per-block argmax
    float4 hv[4];
#pragma unroll
    for (int q = 0; q < 4; ++q) hv[q] = ((const float4*)hS)[lane + (q << 6)];
    unsigned long long wbest = 0ull;
    uint2 K = keys[1 + t];
    float* outrow = out + (size_t)(GN + t) * VOC;
    for (int row = r; row < VOC; row += G4) {
      const float4* w4 = (const float4*)(Wtag + (size_t)row * 1024);
      float acc = 0.0f;
#pragma unroll
      for (int q = 0; q < 4; ++q) {
        float4 w = w4[lane + (q << 6)];
        acc += w.x * hv[q].x + w.y * hv[q].y + w.z * hv[q].z + w.w * hv[q].w;
      }
#pragma unroll
      for (int off = 32; off; off >>= 1) acc += __shfl_xor(acc, off, 64);
      if (lane == 0) {
        float L = acc + btag[row];
        outrow[row] = L;
        float y = L + gumbel_of(K.x, K.y, (uint32_t)row);
        unsigned long long c = packCand(y, row);
        if (c > wbest) wbest = c;
      }
    }
    redU[tid] = wbest;
    __syncthreads();
    for (int s = 128; s; s >>= 1) {
      if (tid < s && redU[tid + s] > redU[tid]) redU[tid] = redU[tid + s];
      __syncthreads();
    }
    if (tid == 0) partials[blockIdx.x] = redU[0];
    __threadfence();
    grid.sync();
    // Phase D: redundant all-block partials reduce -> next token
    unsigned long long b = 0ull;
    for (int i = tid; i < GRID; i += 256) { unsigned long long v = partials[i]; if (v > b) b = v; }
    redU[tid] = b;
    __syncthreads();
    for (int s = 128; s; s >>= 1) {
      if (tid < s && redU[tid + s] > redU[tid]) redU[tid] = redU[tid + s];
      __syncthreads();
    }
    tok = (int)(0xFFFFFFFFu - (uint32_t)(redU[0] & 0xFFFFFFFFull));
    __syncthreads();
  }
}

// ---------------- row-wise log_softmax, in place ----------------
__global__ __launch_bounds__(256) void k_logsoftmax(float* __restrict__ C) {
  __shared__ float red[256];
  float* row = C + (size_t)blockIdx.x * VOC;
  float m = -INFINITY;
  for (int i = threadIdx.x; i < VOC; i += 256) m = fmaxf(m, row[i]);
  red[threadIdx.x] = m;
  __syncthreads();
  for (int s = 128; s; s >>= 1) {
    if (threadIdx.x < s) red[threadIdx.x] = fmaxf(red[threadIdx.x], red[threadIdx.x + s]);
    __syncthreads();
  }
  m = red[0];
  __syncthreads();
  float sum = 0.0f;
  for (int i = threadIdx.x; i < VOC; i += 256) sum += expf(row[i] - m);
  red[threadIdx.x] = sum;
  __syncthreads();
  for (int s = 128; s; s >>= 1) {
    if (threadIdx.x < s) red[threadIdx.x] += red[threadIdx.x + s];
    __syncthreads();
  }
  float lse = m + logf(red[0]);
  __syncthreads();
  for (int i = threadIdx.x; i < VOC; i += 256) row[i] = row[i] - lse;
}

// ---------------- launch ----------------
extern "C" void kernel_launch(void* const* d_in, const int* in_sizes, int n_in,
                              void* d_out, int out_size, void* d_ws, size_t ws_size,
                              hipStream_t stream) {
  (void)in_sizes; (void)n_in; (void)out_size; (void)ws_size;
  const int*   sent  = (const int*)  d_in[0];
  const float* emb   = (const float*)d_in[2];
  const float* Wih_l = (const float*)d_in[3];
  const float* Whh_l = (const float*)d_in[4];
  const float* bih_l = (const float*)d_in[5];
  const float* bhh_l = (const float*)d_in[6];
  const float* Wih_c = (const float*)d_in[7];
  const float* Whh_c = (const float*)d_in[8];
  const float* bih_c = (const float*)d_in[9];
  const float* bhh_c = (const float*)d_in[10];
  const float* Wtag  = (const float*)d_in[11];
  const float* btag  = (const float*)d_in[12];
  float* out = (float*)d_out;

  char* ws = (char*)d_ws;
  uint2*              keys     = (uint2*)(ws + 0);                    // 65*8 B
  unsigned long long* partials = (unsigned long long*)(ws + 1024);    // 8 KB
  float*              gates2   = (float*)(ws + 16384);                // 32 KB
  float*              cbuf     = (float*)(ws + 49152);                // 4 KB
  float*              lstm_out = (float*)(ws + 65536);                // 256 KB
  float*              X        = (float*)(ws + 65536 + 262144);       // 256 KB
  float*              gx       = (float*)(ws + 65536 + 2 * 262144);   // 1 MB

  k_init<<<1, 256, 0, stream>>>(keys);
  k_gather<<<GN, 256, 0, stream>>>(emb, sent, X);
  k_gemm_n32<<<G4 / 32, 256, 0, stream>>>(X, Wih_l, nullptr, gx, G4);

  {
    void* args[] = {(void*)&Whh_l, (void*)&bih_l, (void*)&bhh_l, (void*)&gx,
                    (void*)&gates2, (void*)&lstm_out, (void*)&cbuf};
    hipLaunchCooperativeKernel((const void*)k_prefix_coop, dim3(GRID), dim3(256), args, 0, stream);
  }

  k_gemm_n32<<<VOC / 32, 256, 0, stream>>>(lstm_out, Wtag, btag, out, VOC);

  {
    const float* h_init = lstm_out + (size_t)(GN - 1) * HIDD;
    const float* row63  = out + (size_t)(GN - 1) * VOC;
    void* args[] = {(void*)&Wih_c, (void*)&Whh_c, (void*)&bih_c, (void*)&bhh_c,
                    (void*)&emb, (void*)&Wtag, (void*)&btag,
                    (void*)&h_init, (void*)&cbuf, (void*)&row63,
                    (void*)&keys, (void*)&gates2, (void*)&partials, (void*)&out};
    hipLaunchCooperativeKernel((const void*)k_rollout_coop, dim3(GRID), dim3(256), args, 0, stream);
  }

  k_logsoftmax<<<SEQL, 256, 0, stream>>>(out);
}

// Round 3
// 9815.070 us; speedup vs baseline: 3.7716x; 3.7716x over previous
//
#include <hip/hip_runtime.h>
#include <cstdint>
#include <cstddef>

#define EMBD 1024
#define HIDD 1024
#define G4   4096
#define VOC  32000
#define SEQL 128
#define GN   64
#define NR   64
#define RGRID 500          // rollout fused kernel: 500 blocks (64 logits rows each)
#define PPROD 256          // producer blocks computing gates (16 rows each)

#define JAX_PARTITIONABLE 1

// ---------------- threefry2x32 (JAX-compatible, 20 rounds) ----------------
__device__ __forceinline__ uint32_t rotl32(uint32_t v, int d) { return (v << d) | (v >> (32 - d)); }

__device__ inline void threefry2x32(uint32_t k0, uint32_t k1, uint32_t x0, uint32_t x1,
                                    uint32_t& o0, uint32_t& o1) {
  uint32_t ks2 = k0 ^ k1 ^ 0x1BD11BDAu;
#define TF_ROUND(r) { x0 += x1; x1 = rotl32(x1, r); x1 ^= x0; }
  x0 += k0;  x1 += k1;
  TF_ROUND(13) TF_ROUND(15) TF_ROUND(26) TF_ROUND(6)
  x0 += k1;  x1 += ks2 + 1u;
  TF_ROUND(17) TF_ROUND(29) TF_ROUND(16) TF_ROUND(24)
  x0 += ks2; x1 += k0 + 2u;
  TF_ROUND(13) TF_ROUND(15) TF_ROUND(26) TF_ROUND(6)
  x0 += k0;  x1 += k1 + 3u;
  TF_ROUND(17) TF_ROUND(29) TF_ROUND(16) TF_ROUND(24)
  x0 += k1;  x1 += ks2 + 4u;
  TF_ROUND(13) TF_ROUND(15) TF_ROUND(26) TF_ROUND(6)
  x0 += ks2; x1 += k0 + 5u;
#undef TF_ROUND
  o0 = x0; o1 = x1;
}

__device__ inline uint32_t rng_bits(uint32_t k0, uint32_t k1, uint32_t idx) {
#if JAX_PARTITIONABLE
  uint32_t h0, h1; threefry2x32(k0, k1, 0u, idx, h0, h1);
  return h0 ^ h1;
#else
  uint32_t h0, h1;
  if (idx < (VOC / 2)) { threefry2x32(k0, k1, idx, idx + (VOC / 2), h0, h1); return h0; }
  else                 { threefry2x32(k0, k1, idx - (VOC / 2), idx, h0, h1); return h1; }
#endif
}

__device__ inline float gumbel_of(uint32_t k0, uint32_t k1, uint32_t idx) {
  uint32_t bits = rng_bits(k0, k1, idx);
  float u = __uint_as_float((bits >> 9) | 0x3f800000u) - 1.0f;
  u = fmaxf(u, 1.17549435e-38f);
  return -logf(-logf(u));
}

__device__ inline unsigned long long packCand(float v, int idx) {
  uint32_t u = __float_as_uint(v);
  u = (u & 0x80000000u) ? ~u : (u | 0x80000000u);
  return ((unsigned long long)u << 32) | (unsigned long long)(0xFFFFFFFFu - (uint32_t)idx);
}

__device__ inline float sigf(float x) { return 1.0f / (1.0f + expf(-x)); }

// ---------------- init: keys, counters, zero state ----------------
__global__ void k_init(uint2* keys, unsigned* counters, float* cbuf, float* h0) {
  int t = threadIdx.x;
  if (t < NR + 1) {
    uint32_t a, b; threefry2x32(0u, 123u, 0u, (uint32_t)t, a, b);
    keys[t] = make_uint2(a, b);
  }
  if (t < 192) counters[t] = 0u;
  for (int i = t; i < HIDD; i += 256) { cbuf[i] = 0.0f; h0[i] = 0.0f; }
}

// ---------------- gather prefix embeddings ----------------
__global__ void k_gather(const float* __restrict__ emb, const int* __restrict__ sent,
                         float* __restrict__ X) {
  int m = blockIdx.x;
  int row = sent[m];
  const float4* s = (const float4*)(emb + (size_t)row * EMBD);
  float4* d = (float4*)(X + (size_t)m * EMBD);
  d[threadIdx.x] = s[threadIdx.x];
}

// ---------------- GEMM: C[64][N] = A[64][1024] @ B[N][1024]^T (+bias), 32-col tiles ----------------
__global__ __launch_bounds__(256) void k_gemm_n32(const float* __restrict__ A,
                                                  const float* __restrict__ B,
                                                  const float* __restrict__ bias,
                                                  float* __restrict__ C, int ldc) {
  __shared__ float As[64][33];
  __shared__ float Bs[32][33];
  int n0 = blockIdx.x * 32;
  int tn = threadIdx.x & 15, tm = threadIdx.x >> 4;
  float acc[4][2] = {{0.f}};
  for (int k0 = 0; k0 < 1024; k0 += 32) {
    for (int f = threadIdx.x; f < 512; f += 256) {
      int r = f >> 3, c4 = (f & 7) << 2;
      float4 v = *(const float4*)(A + (size_t)r * 1024 + k0 + c4);
      As[r][c4 + 0] = v.x; As[r][c4 + 1] = v.y; As[r][c4 + 2] = v.z; As[r][c4 + 3] = v.w;
    }
    {
      int f = threadIdx.x;
      int r = f >> 3, c4 = (f & 7) << 2;
      float4 u = *(const float4*)(B + (size_t)(n0 + r) * 1024 + k0 + c4);
      Bs[r][c4 + 0] = u.x; Bs[r][c4 + 1] = u.y; Bs[r][c4 + 2] = u.z; Bs[r][c4 + 3] = u.w;
    }
    __syncthreads();
#pragma unroll
    for (int kk = 0; kk < 32; ++kk) {
      float a0 = As[tm * 4 + 0][kk], a1 = As[tm * 4 + 1][kk];
      float a2 = As[tm * 4 + 2][kk], a3 = As[tm * 4 + 3][kk];
      float b0 = Bs[tn * 2 + 0][kk], b1 = Bs[tn * 2 + 1][kk];
      acc[0][0] += a0 * b0; acc[0][1] += a0 * b1;
      acc[1][0] += a1 * b0; acc[1][1] += a1 * b1;
      acc[2][0] += a2 * b0; acc[2][1] += a2 * b1;
      acc[3][0] += a3 * b0; acc[3][1] += a3 * b1;
    }
    __syncthreads();
  }
#pragma unroll
  for (int i = 0; i < 4; ++i)
#pragma unroll
    for (int j = 0; j < 2; ++j) {
      int m = tm * 4 + i, n = n0 + tn * 2 + j;
      C[(size_t)m * ldc + n] = acc[i][j] + (bias ? bias[n] : 0.0f);
    }
}

// ---------------- prefix LSTM step (R1-proven) ----------------
__global__ __launch_bounds__(256) void k_lstm_pre(const float* __restrict__ Whh,
                                                  const float* __restrict__ bih,
                                                  const float* __restrict__ bhh,
                                                  const float* __restrict__ gx, int t,
                                                  const float* __restrict__ hprev,
                                                  float* __restrict__ cbuf,
                                                  float* __restrict__ hout) {
  __shared__ float gs[4];
  int wave = threadIdx.x >> 6, lane = threadIdx.x & 63;
  int j = blockIdx.x;
  int r = j + (wave << 10);
  const float4* h4 = (const float4*)hprev;
  const float4* w4 = (const float4*)(Whh + (size_t)r * 1024);
  float a = 0.0f;
#pragma unroll
  for (int q = 0; q < 4; ++q) {
    float4 w = w4[lane + (q << 6)];
    float4 h = h4[lane + (q << 6)];
    a += w.x * h.x + w.y * h.y + w.z * h.z + w.w * h.w;
  }
#pragma unroll
  for (int off = 32; off; off >>= 1) a += __shfl_xor(a, off, 64);
  if (lane == 0) gs[wave] = a + gx[(size_t)t * G4 + r] + bih[r] + bhh[r];
  __syncthreads();
  if (threadIdx.x == 0) {
    float gi = gs[0], gf = gs[1], gg = gs[2], go = gs[3];
    float cn = sigf(gf) * cbuf[j] + sigf(gi) * tanhf(gg);
    cbuf[j] = cn;
    hout[j] = sigf(go) * tanhf(cn);
  }
}

// ---------------- initial sample (R1-proven) ----------------
__global__ __launch_bounds__(256) void k_sample_row(const float* __restrict__ row,
                                                    const uint2* __restrict__ keys, int key_idx,
                                                    unsigned long long* __restrict__ partials,
                                                    unsigned* __restrict__ counter,
                                                    int* __restrict__ token_out) {
  __shared__ unsigned long long red[256];
  __shared__ int amLast;
  int v = blockIdx.x * 256 + threadIdx.x;
  unsigned long long best = 0ull;
  if (v < VOC) {
    uint2 K = keys[key_idx];
    float y = row[v] + gumbel_of(K.x, K.y, (uint32_t)v);
    best = packCand(y, v);
  }
  red[threadIdx.x] = best;
  __syncthreads();
  for (int s = 128; s; s >>= 1) {
    if (threadIdx.x < s && red[threadIdx.x + s] > red[threadIdx.x]) red[threadIdx.x] = red[threadIdx.x + s];
    __syncthreads();
  }
  if (threadIdx.x == 0) partials[blockIdx.x] = red[0];
  __threadfence();
  __syncthreads();
  if (threadIdx.x == 0) amLast = (atomicAdd(counter, 1u) == gridDim.x - 1) ? 1 : 0;
  __syncthreads();
  if (amLast) {
    __threadfence();
    unsigned long long b = 0ull;
    for (int i = threadIdx.x; i < (int)gridDim.x; i += 256) {
      unsigned long long val = __hip_atomic_load(partials + i, __ATOMIC_RELAXED, __HIP_MEMORY_SCOPE_AGENT);
      if (val > b) b = val;
    }
    red[threadIdx.x] = b;
    __syncthreads();
    for (int s = 128; s; s >>= 1) {
      if (threadIdx.x < s && red[threadIdx.x + s] > red[threadIdx.x]) red[threadIdx.x] = red[threadIdx.x + s];
      __syncthreads();
    }
    if (threadIdx.x == 0)
      token_out[0] = (int)(0xFFFFFFFFu - (uint32_t)(red[0] & 0xFFFFFFFFull));
  }
}

// ---------------- fused rollout step: gates (blocks 0..255) -> flag -> h/c -> logits+sample ----------------
__global__ __launch_bounds__(256) void k_roll_step(const float* __restrict__ Wih,
                                                   const float* __restrict__ Whh,
                                                   const float* __restrict__ bih,
                                                   const float* __restrict__ bhh,
                                                   const float* __restrict__ emb,
                                                   const float* __restrict__ Wtag,
                                                   const float* __restrict__ btag,
                                                   const int* __restrict__ tok_in,
                                                   const float* __restrict__ hprev,
                                                   const float* __restrict__ cprev,
                                                   float* __restrict__ hnext,
                                                   float* __restrict__ cnext,
                                                   float* __restrict__ gates,
                                                   unsigned* __restrict__ gate_ctr,
                                                   const uint2* __restrict__ keys, int key_idx,
                                                   float* __restrict__ outrow,
                                                   unsigned long long* __restrict__ partials,
                                                   unsigned* __restrict__ red_ctr,
                                                   int* __restrict__ token_out) {
  __shared__ __align__(16) float hS[1024];
  __shared__ unsigned long long bw[4];
  __shared__ unsigned long long red[256];
  __shared__ int amLast;
  int tid = threadIdx.x, wave = tid >> 6, lane = tid & 63;

  // ---- Phase P: producers (blocks 0..255) compute 16 gate rows each ----
  if (blockIdx.x < PPROD) {
    int tok = tok_in[0];
    const float4* x4 = (const float4*)(emb + (size_t)tok * EMBD);
    const float4* h4 = (const float4*)hprev;
#pragma unroll
    for (int rr = 0; rr < 4; ++rr) {
      int row = blockIdx.x * 16 + wave * 4 + rr;
      const float4* wi4 = (const float4*)(Wih + (size_t)row * 1024);
      const float4* wh4 = (const float4*)(Whh + (size_t)row * 1024);
      float a = 0.0f;
#pragma unroll
      for (int q = 0; q < 4; ++q) {
        float4 w = wi4[lane + (q << 6)];
        float4 x = x4[lane + (q << 6)];
        a += w.x * x.x + w.y * x.y + w.z * x.z + w.w * x.w;
        w = wh4[lane + (q << 6)];
        float4 h = h4[lane + (q << 6)];
        a += w.x * h.x + w.y * h.y + w.z * h.z + w.w * h.w;
      }
#pragma unroll
      for (int off = 32; off; off >>= 1) a += __shfl_xor(a, off, 64);
      if (lane == 0) gates[row] = a + bih[row] + bhh[row];
    }
  }
  __syncthreads();
  if (blockIdx.x < PPROD && tid == 0) {
    __threadfence();
    __hip_atomic_fetch_add(gate_ctr, 1u, __ATOMIC_RELEASE, __HIP_MEMORY_SCOPE_AGENT);
  }

  // ---- Phase W: all blocks wait for all gates ----
  if (tid == 0) {
    while (__hip_atomic_load(gate_ctr, __ATOMIC_ACQUIRE, __HIP_MEMORY_SCOPE_AGENT) < (unsigned)PPROD)
      __builtin_amdgcn_s_sleep(1);
  }
  __syncthreads();

  // ---- Phase H: redundant h/c update into LDS (gates via agent-scope loads) ----
  for (int j = tid; j < 1024; j += 256) {
    float gi = __hip_atomic_load(gates + j,        __ATOMIC_RELAXED, __HIP_MEMORY_SCOPE_AGENT);
    float gf = __hip_atomic_load(gates + j + 1024, __ATOMIC_RELAXED, __HIP_MEMORY_SCOPE_AGENT);
    float gg = __hip_atomic_load(gates + j + 2048, __ATOMIC_RELAXED, __HIP_MEMORY_SCOPE_AGENT);
    float go = __hip_atomic_load(gates + j + 3072, __ATOMIC_RELAXED, __HIP_MEMORY_SCOPE_AGENT);
    float cn = sigf(gf) * cprev[j] + sigf(gi) * tanhf(gg);
    float hn = sigf(go) * tanhf(cn);
    hS[j] = hn;
    if (blockIdx.x == 0) { cnext[j] = cn; hnext[j] = hn; }
  }
  __syncthreads();

  // ---- Phase L: logits rows [b*64, b*64+64), gumbel + per-block argmax ----
  float4 hv[4];
#pragma unroll
  for (int q = 0; q < 4; ++q) hv[q] = ((const float4*)hS)[lane + (q << 6)];
  unsigned long long wbest = 0ull;
  uint2 K = keys[key_idx];
  int r0 = blockIdx.x * 64;
  for (int rr = 0; rr < 16; ++rr) {
    int row = r0 + wave * 16 + rr;
    const float4* w4 = (const float4*)(Wtag + (size_t)row * 1024);
    float acc = 0.0f;
#pragma unroll
    for (int q = 0; q < 4; ++q) {
      float4 w = w4[lane + (q << 6)];
      acc += w.x * hv[q].x + w.y * hv[q].y + w.z * hv[q].z + w.w * hv[q].w;
    }
#pragma unroll
    for (int off = 32; off; off >>= 1) acc += __shfl_xor(acc, off, 64);
    if (lane == 0) {
      float L = acc + btag[row];
      outrow[row] = L;
      float y = L + gumbel_of(K.x, K.y, (uint32_t)row);
      unsigned long long c = packCand(y, row);
      if (c > wbest) wbest = c;
    }
  }
  if (lane == 0) bw[wave] = wbest;
  __syncthreads();
  if (tid == 0) {
    unsigned long long b = bw[0];
#pragma unroll
    for (int w = 1; w < 4; ++w) if (bw[w] > b) b = bw[w];
    partials[blockIdx.x] = b;
  }
  __threadfence();
  __syncthreads();
  if (tid == 0) amLast = (atomicAdd(red_ctr, 1u) == gridDim.x - 1) ? 1 : 0;
  __syncthreads();
  if (amLast) {
    __threadfence();
    unsigned long long b = 0ull;
    for (int i = tid; i < (int)gridDim.x; i += 256) {
      unsigned long long v = __hip_atomic_load(partials + i, __ATOMIC_RELAXED, __HIP_MEMORY_SCOPE_AGENT);
      if (v > b) b = v;
    }
    red[tid] = b;
    __syncthreads();
    for (int s = 128; s; s >>= 1) {
      if (tid < s && red[tid + s] > red[tid]) red[tid] = red[tid + s];
      __syncthreads();
    }
    if (tid == 0)
      token_out[0] = (int)(0xFFFFFFFFu - (uint32_t)(red[0] & 0xFFFFFFFFull));
  }
}

// ---------------- row-wise log_softmax, in place ----------------
__global__ __launch_bounds__(256) void k_logsoftmax(float* __restrict__ C) {
  __shared__ float red[256];
  float* row = C + (size_t)blockIdx.x * VOC;
  float m = -INFINITY;
  for (int i = threadIdx.x; i < VOC; i += 256) m = fmaxf(m, row[i]);
  red[threadIdx.x] = m;
  __syncthreads();
  for (int s = 128; s; s >>= 1) {
    if (threadIdx.x < s) red[threadIdx.x] = fmaxf(red[threadIdx.x], red[threadIdx.x + s]);
    __syncthreads();
  }
  m = red[0];
  __syncthreads();
  float sum = 0.0f;
  for (int i = threadIdx.x; i < VOC; i += 256) sum += expf(row[i] - m);
  red[threadIdx.x] = sum;
  __syncthreads();
  for (int s = 128; s; s >>= 1) {
    if (threadIdx.x < s) red[threadIdx.x] += red[threadIdx.x + s];
    __syncthreads();
  }
  float lse = m + logf(red[0]);
  __syncthreads();
  for (int i = threadIdx.x; i < VOC; i += 256) row[i] = row[i] - lse;
}

// ---------------- launch ----------------
extern "C" void kernel_launch(void* const* d_in, const int* in_sizes, int n_in,
                              void* d_out, int out_size, void* d_ws, size_t ws_size,
                              hipStream_t stream) {
  (void)in_sizes; (void)n_in; (void)out_size; (void)ws_size;
  const int*   sent  = (const int*)  d_in[0];
  const float* emb   = (const float*)d_in[2];
  const float* Wih_l = (const float*)d_in[3];
  const float* Whh_l = (const float*)d_in[4];
  const float* bih_l = (const float*)d_in[5];
  const float* bhh_l = (const float*)d_in[6];
  const float* Wih_c = (const float*)d_in[7];
  const float* Whh_c = (const float*)d_in[8];
  const float* bih_c = (const float*)d_in[9];
  const float* bhh_c = (const float*)d_in[10];
  const float* Wtag  = (const float*)d_in[11];
  const float* btag  = (const float*)d_in[12];
  float* out = (float*)d_out;

  char* ws = (char*)d_ws;
  uint2*              keys     = (uint2*)(ws + 0);                 // 65*8 B
  int*                tokens   = (int*)(ws + 1024);                // 65*4 B
  unsigned*           counters = (unsigned*)(ws + 2048);           // 192*4 B
  unsigned long long* partials = (unsigned long long*)(ws + 4096); // 500*8 B
  float*              cbuf_pre = (float*)(ws + 8192);              // 4 KB
  float*              h0       = (float*)(ws + 12288);             // 4 KB
  float*              gbuf     = (float*)(ws + 16384);             // 2*16 KB
  float*              croll    = (float*)(ws + 49152);             // 2*4 KB
  float*              hroll    = (float*)(ws + 57344);             // 2*4 KB
  float*              lstm_out = (float*)(ws + 65536);             // 256 KB
  float*              X        = (float*)(ws + 65536 + 262144);    // 256 KB
  float*              gx       = (float*)(ws + 65536 + 2*262144);  // 1 MB

  k_init<<<1, 256, 0, stream>>>(keys, counters, cbuf_pre, h0);
  k_gather<<<GN, 256, 0, stream>>>(emb, sent, X);
  k_gemm_n32<<<G4 / 32, 256, 0, stream>>>(X, Wih_l, nullptr, gx, G4);

  for (int t = 0; t < GN; ++t) {
    const float* hp = t ? (lstm_out + (size_t)(t - 1) * HIDD) : h0;
    k_lstm_pre<<<HIDD, 256, 0, stream>>>(Whh_l, bih_l, bhh_l, gx, t, hp, cbuf_pre,
                                         lstm_out + (size_t)t * HIDD);
  }

  k_gemm_n32<<<VOC / 32, 256, 0, stream>>>(lstm_out, Wtag, btag, out, VOC);

  k_sample_row<<<(VOC + 255) / 256, 256, 0, stream>>>(out + (size_t)(GN - 1) * VOC, keys, 0,
                                                      partials, counters + 128, tokens);

  for (int t = 0; t < NR; ++t) {
    const float* hp = t ? (hroll + (size_t)(t & 1) * HIDD) : (lstm_out + (size_t)(GN - 1) * HIDD);
    const float* cp = t ? (croll + (size_t)(t & 1) * HIDD) : cbuf_pre;
    float* hn = hroll + (size_t)((t + 1) & 1) * HIDD;
    float* cn = croll + (size_t)((t + 1) & 1) * HIDD;
    float* g  = gbuf + (size_t)(t & 1) * G4;
    k_roll_step<<<RGRID, 256, 0, stream>>>(Wih_c, Whh_c, bih_c, bhh_c, emb, Wtag, btag,
                                           tokens + t, hp, cp, hn, cn, g,
                                           counters + t, keys, 1 + t,
                                           out + (size_t)(GN + t) * VOC,
                                           partials, counters + 64 + t, tokens + t + 1);
  }

  k_logsoftmax<<<SEQL, 256, 0, stream>>>(out);
}